// Round 1
// baseline (3204.600 us; speedup 1.0000x reference)
//
#include <hip/hip_runtime.h>
#include <cstdint>
#include <cstddef>
#include <math.h>

// AtomSelector: B=4096 batch, A=4096 atoms, H=768 hidden, L=4 steps.
// Output is (numerically) one-hot selections of gumbel-softmax argmax.
// PRNG: JAX threefry2x32, PARTITIONABLE scheme (jax>=0.4.30 default):
//   split: newkey = TF(key,(0,0)), sub = TF(key,(0,1))   [fold-like]
//   bits[i] = out0 ^ out1 of TF(sub, (hi32(i), lo32(i)))
// PLAN B (if absmax=1.0 persists): original non-partitionable scheme:
//   split: counts [0,1,2,3] paired (0,2),(1,3); key=(o0(0,2),o0(1,3)), sub=(o1...)
//   bits: pairs (i, i+size/2), low half takes o0, high half o1.

#define KB 4096
#define KA 4096
#define KH 768
#define KL 4

__host__ __device__ inline unsigned rotl32(unsigned x, int d) {
  return (x << d) | (x >> (32 - d));
}

// Threefry-2x32, 20 rounds (matches jax._src.prng threefry2x32 lowering)
__host__ __device__ inline void tf2x32(unsigned k0, unsigned k1,
                                       unsigned x0, unsigned x1,
                                       unsigned& o0, unsigned& o1) {
  unsigned ks2 = k0 ^ k1 ^ 0x1BD11BDAu;
  x0 += k0; x1 += k1;
#define TF_R(r) { x0 += x1; x1 = rotl32(x1, (r)); x1 ^= x0; }
  TF_R(13) TF_R(15) TF_R(26) TF_R(6)
  x0 += k1;  x1 += ks2 + 1u;
  TF_R(17) TF_R(29) TF_R(16) TF_R(24)
  x0 += ks2; x1 += k0 + 2u;
  TF_R(13) TF_R(15) TF_R(26) TF_R(6)
  x0 += k0;  x1 += k1 + 3u;
  TF_R(17) TF_R(29) TF_R(16) TF_R(24)
  x0 += k1;  x1 += ks2 + 4u;
  TF_R(13) TF_R(15) TF_R(26) TF_R(6)
  x0 += ks2; x1 += k0 + 5u;
#undef TF_R
  o0 = x0; o1 = x1;
}

// ---------------------------------------------------------------------------
// C[M,N] = A[M,K=768] @ W[N,K=768]^T   (fp32 vector FMA; no fp32 MFMA on CDNA4)
// BM=BN=128, BK=16, 256 threads, 8x8 micro-tile per thread.
// LDS padded to stride 132 (132%32==4 -> max 2-way bank aliasing, free).
// ---------------------------------------------------------------------------
__global__ __launch_bounds__(256) void gemm_nt(
    const float* __restrict__ A, const float* __restrict__ W,
    float* __restrict__ C, long long ldc) {
  __shared__ float As[16][132];
  __shared__ float Ws[16][132];
  const int tid = threadIdx.x;
  const int bm = blockIdx.y * 128;
  const int bn = blockIdx.x * 128;
  const int tx = tid & 15;   // -> 2x4 column quads (tx*4 and 64+tx*4)
  const int ty = tid >> 4;   // -> 8 rows (ty*8..)
  const int lrow = tid >> 2; // loader: 0..63
  const int lkq  = tid & 3;  // loader: which float4 along K

  float acc[8][8];
#pragma unroll
  for (int i = 0; i < 8; ++i)
#pragma unroll
    for (int jj = 0; jj < 8; ++jj) acc[i][jj] = 0.f;

  for (int k0 = 0; k0 < KH; k0 += 16) {
#pragma unroll
    for (int it = 0; it < 2; ++it) {
      int row = lrow + it * 64;
      float4 av = *(const float4*)(A + (size_t)(bm + row) * KH + k0 + lkq * 4);
      As[lkq * 4 + 0][row] = av.x; As[lkq * 4 + 1][row] = av.y;
      As[lkq * 4 + 2][row] = av.z; As[lkq * 4 + 3][row] = av.w;
      float4 wv = *(const float4*)(W + (size_t)(bn + row) * KH + k0 + lkq * 4);
      Ws[lkq * 4 + 0][row] = wv.x; Ws[lkq * 4 + 1][row] = wv.y;
      Ws[lkq * 4 + 2][row] = wv.z; Ws[lkq * 4 + 3][row] = wv.w;
    }
    __syncthreads();
#pragma unroll
    for (int k = 0; k < 16; ++k) {
      float4 a0 = *(const float4*)&As[k][ty * 8];
      float4 a1 = *(const float4*)&As[k][ty * 8 + 4];
      float4 w0 = *(const float4*)&Ws[k][tx * 4];
      float4 w1 = *(const float4*)&Ws[k][64 + tx * 4];
      float a[8] = {a0.x, a0.y, a0.z, a0.w, a1.x, a1.y, a1.z, a1.w};
      float w[8] = {w0.x, w0.y, w0.z, w0.w, w1.x, w1.y, w1.z, w1.w};
#pragma unroll
      for (int i = 0; i < 8; ++i)
#pragma unroll
        for (int jj = 0; jj < 8; ++jj)
          acc[i][jj] = fmaf(a[i], w[jj], acc[i][jj]);
    }
    __syncthreads();
  }
#pragma unroll
  for (int i = 0; i < 8; ++i) {
    size_t m = (size_t)(bm + ty * 8 + i);
    float4 c0 = make_float4(acc[i][0], acc[i][1], acc[i][2], acc[i][3]);
    float4 c1 = make_float4(acc[i][4], acc[i][5], acc[i][6], acc[i][7]);
    *(float4*)(C + m * ldc + bn + tx * 4) = c0;
    *(float4*)(C + m * ldc + bn + 64 + tx * 4) = c1;
  }
}

// X[b,:] = cls[b,:] + ae_weight[idx[b],:]   (float4 over B*H/4)
__global__ void build_x(const float* __restrict__ cls, const float* __restrict__ aew,
                        const int* __restrict__ idxbuf, float* __restrict__ X) {
  int i = blockIdx.x * 256 + threadIdx.x;
  int b = i / (KH / 4);
  int c = i - b * (KH / 4);
  int idx = idxbuf[b];
  float4 cv = ((const float4*)cls)[i];
  float4 av = ((const float4*)(aew + (size_t)idx * KH))[c];
  ((float4*)X)[i] = make_float4(cv.x + av.x, cv.y + av.y, cv.z + av.z, cv.w + av.w);
}

// GRU gates; h updated in place. first=1: h_prev=0, Gh ignored (gh = b_hh only).
__global__ void gru_gate(const float* __restrict__ Gi, const float* __restrict__ Gh,
                         const float* __restrict__ b_ih, const float* __restrict__ b_hh,
                         float* __restrict__ h, int first) {
  int i = blockIdx.x * 256 + threadIdx.x;  // over B*H
  int b = i / KH, c = i - b * KH;
  const float* gi = Gi + (size_t)b * (3 * KH);
  float ir  = gi[c]          + b_ih[c];
  float iz  = gi[c + KH]     + b_ih[c + KH];
  float in_ = gi[c + 2 * KH] + b_ih[c + 2 * KH];
  float hr = b_hh[c], hz = b_hh[c + KH], hn = b_hh[c + 2 * KH];
  float hp = 0.f;
  if (!first) {
    const float* gh = Gh + (size_t)b * (3 * KH);
    hr += gh[c]; hz += gh[c + KH]; hn += gh[c + 2 * KH];
    hp = h[i];
  }
  float r = 1.f / (1.f + expf(-(ir + hr)));
  float z = 1.f / (1.f + expf(-(iz + hz)));
  float n = tanhf(in_ + r * hn);
  h[i] = (1.f - z) * n + z * hp;
}

// One block per batch row. Reads logits (head matmul already in d_out row),
// adds head_b + gumbel, applies mask state machine, argmax (first-max tie
// break like jnp.argmax), overwrites the row with one-hot, updates mask/idx.
__global__ __launch_bounds__(256) void sample_step(
    float* __restrict__ out, const float* __restrict__ head_b,
    const float* __restrict__ x_, unsigned char* __restrict__ mask,
    int* __restrict__ idxbuf, int j, unsigned s0, unsigned s1) {
  const int b = blockIdx.x;
  const int tid = threadIdx.x;
  float* orow = out + ((size_t)b * KL + j) * KA;
  unsigned char* mrow = mask + (size_t)b * KA;
  const float* xrow = x_ + (size_t)b * KA;
  __shared__ float sv[256];
  __shared__ int si[256];

  int idx_prev = 0;
  if (j > 0) idx_prev = idxbuf[b];

  int empty = 0;
  if (j == 0) {
    int cnt = 0;
#pragma unroll
    for (int t = 0; t < 16; ++t) cnt += (xrow[tid + (t << 8)] != 0.f) ? 1 : 0;
    si[tid] = cnt;
    __syncthreads();
    for (int s = 128; s > 0; s >>= 1) {
      if (tid < s) si[tid] += si[tid + s];
      __syncthreads();
    }
    empty = (si[0] == 0);
    __syncthreads();
  }

  float best = -INFINITY;
  int bi = KA;
  unsigned mbits = 0;
#pragma unroll
  for (int t = 0; t < 16; ++t) {
    int a = tid + (t << 8);
    int m;
    if (j == 0) {
      m = (xrow[a] != 0.f) ? 1 : 0;
      if (empty && a == 0) m = 1;
    } else {
      m = mrow[a];
      if (idx_prev == 0) m = 0;
      if (a == 0) m = 1;
    }
    float v = -INFINITY;
    if (m) {
      // JAX partitionable random_bits: TF(sub, hi=0, lo=i), xor halves.
      unsigned o0, o1;
      tf2x32(s0, s1, 0u, (unsigned)(b * KA + a), o0, o1);
      unsigned bits = o0 ^ o1;
      // jax.random.uniform(minval=tiny, maxval=1): ((bits>>9)|1.0f bits)-1,
      // then f*(1-tiny)+tiny == f+tiny, clamped at tiny.
      float f = __uint_as_float((bits >> 9) | 0x3f800000u) - 1.0f;
      const float TINY = 1.17549435e-38f;
      float u = fmaxf(TINY, f + TINY);
      float g = -logf(-logf(u));
      v = orow[a] + head_b[a] + g;
      mbits |= (1u << t);
    }
    if (v > best || (v == best && a < bi)) { best = v; bi = a; }
  }
  sv[tid] = best; si[tid] = bi;
  __syncthreads();
  for (int s = 128; s > 0; s >>= 1) {
    if (tid < s) {
      float v2 = sv[tid + s]; int i2 = si[tid + s];
      if (v2 > sv[tid] || (v2 == sv[tid] && i2 < si[tid])) { sv[tid] = v2; si[tid] = i2; }
    }
    __syncthreads();
  }
  const int sel = si[0];
#pragma unroll
  for (int t = 0; t < 16; ++t) {
    int a = tid + (t << 8);
    int m = (mbits >> t) & 1;
    if (a == sel) m = 0;
    mrow[a] = (unsigned char)m;
    orow[a] = (a == sel) ? 1.f : 0.f;
  }
  if (tid == 0) idxbuf[b] = sel;
}

extern "C" void kernel_launch(void* const* d_in, const int* in_sizes, int n_in,
                              void* d_out, int out_size, void* d_ws, size_t ws_size,
                              hipStream_t stream) {
  const float* cls    = (const float*)d_in[0];
  const float* x_     = (const float*)d_in[1];
  const float* w_ih   = (const float*)d_in[2];
  const float* w_hh   = (const float*)d_in[3];
  const float* b_ih   = (const float*)d_in[4];
  const float* b_hh   = (const float*)d_in[5];
  const float* head_w = (const float*)d_in[6];
  const float* head_b = (const float*)d_in[7];
  const float* ae_w   = (const float*)d_in[8];
  float* out = (float*)d_out;

  char* p = (char*)d_ws;
  float* X    = (float*)p; p += (size_t)KB * KH * 4;      // 12.6 MB
  float* hbuf = (float*)p; p += (size_t)KB * KH * 4;      // 12.6 MB
  float* Gi   = (float*)p; p += (size_t)KB * 3 * KH * 4;  // 37.7 MB
  float* Gh   = (float*)p; p += (size_t)KB * 3 * KH * 4;  // 37.7 MB
  unsigned char* mask = (unsigned char*)p; p += (size_t)KB * KA;  // 16.8 MB
  int* idxbuf = (int*)p; p += (size_t)KB * 4;

  // Host-side key schedule: key(42) -> per-step subkeys (fold-like split).
  unsigned key0 = 0u, key1 = 42u;
  unsigned sub0[KL], sub1[KL];
  for (int j = 0; j < KL; ++j) {
    unsigned n0, n1, t0, t1;
    tf2x32(key0, key1, 0u, 0u, n0, n1);  // new carry key
    tf2x32(key0, key1, 0u, 1u, t0, t1);  // subkey for this step's gumbel
    sub0[j] = t0; sub1[j] = t1;
    key0 = n0; key1 = n1;
  }

  for (int j = 0; j < KL; ++j) {
    const float* xin = cls;
    if (j > 0) {
      build_x<<<KB * KH / 4 / 256, 256, 0, stream>>>(cls, ae_w, idxbuf, X);
      xin = X;
    }
    // gi = x @ w_ih^T
    gemm_nt<<<dim3(3 * KH / 128, KB / 128), 256, 0, stream>>>(xin, w_ih, Gi, 3 * KH);
    // gh = h @ w_hh^T (h==0 at j==0: skipped, gate uses b_hh only)
    if (j > 0)
      gemm_nt<<<dim3(3 * KH / 128, KB / 128), 256, 0, stream>>>(hbuf, w_hh, Gh, 3 * KH);
    gru_gate<<<KB * KH / 256, 256, 0, stream>>>(Gi, Gh, b_ih, b_hh, hbuf, j == 0);
    // logits (sans bias) straight into d_out[:, j, :]
    gemm_nt<<<dim3(KA / 128, KB / 128), 256, 0, stream>>>(
        hbuf, head_w, out + (size_t)j * KA, (long long)KL * KA);
    sample_step<<<KB, 256, 0, stream>>>(out, head_b, x_, mask, idxbuf, j,
                                        sub0[j], sub1[j]);
  }
}

// Round 2
// 1342.145 us; speedup vs baseline: 2.3877x; 2.3877x over previous
//
#include <hip/hip_runtime.h>
#include <cstdint>
#include <cstddef>
#include <math.h>

// AtomSelector: B=4096, A=4096, H=768, L=4.
// R1: GEMMs moved to MFMA (bf16x2 split, 3 products: hihi + hilo + lohi).
// PRNG: JAX threefry2x32 partitionable scheme (verified exact in R0).

#define KB 4096
#define KA 4096
#define KH 768
#define KL 4

typedef __attribute__((ext_vector_type(8))) short bf16x8;
typedef __attribute__((ext_vector_type(4))) float f32x4;

__host__ __device__ inline unsigned rotl32(unsigned x, int d) {
  return (x << d) | (x >> (32 - d));
}

// Threefry-2x32, 20 rounds
__host__ __device__ inline void tf2x32(unsigned k0, unsigned k1,
                                       unsigned x0, unsigned x1,
                                       unsigned& o0, unsigned& o1) {
  unsigned ks2 = k0 ^ k1 ^ 0x1BD11BDAu;
  x0 += k0; x1 += k1;
#define TF_R(r) { x0 += x1; x1 = rotl32(x1, (r)); x1 ^= x0; }
  TF_R(13) TF_R(15) TF_R(26) TF_R(6)
  x0 += k1;  x1 += ks2 + 1u;
  TF_R(17) TF_R(29) TF_R(16) TF_R(24)
  x0 += ks2; x1 += k0 + 2u;
  TF_R(13) TF_R(15) TF_R(26) TF_R(6)
  x0 += k0;  x1 += k1 + 3u;
  TF_R(17) TF_R(29) TF_R(16) TF_R(24)
  x0 += k1;  x1 += ks2 + 4u;
  TF_R(13) TF_R(15) TF_R(26) TF_R(6)
  x0 += ks2; x1 += k0 + 5u;
#undef TF_R
  o0 = x0; o1 = x1;
}

__device__ inline ushort f2bf(float f) {
  unsigned u = __float_as_uint(f);
  unsigned r = (u + 0x7fffu + ((u >> 16) & 1u)) >> 16;
  return (ushort)r;
}
__device__ inline float bf2f(ushort h) {
  return __uint_as_float(((unsigned)h) << 16);
}

// ---------------------------------------------------------------------------
// C[M,N] = A[M,768] @ W[N,768]^T via bf16x2-split MFMA.
// A,W given as bf16 hi/lo planes ([*,768] row-major ushort).
// 256 thr / 4 waves; BM=BN=128, BK=64; wave -> 64x64 (4x4 of 16x16 tiles).
// LDS: 4 planes x 128x64 bf16 = 64KB, staged via global_load_lds width=16
// with chunk-slot XOR swizzle (slot = chunk ^ (row&7)): staging stays
// lane-contiguous; ds_read_b128 gets only the free 2-way bank aliasing.
// ---------------------------------------------------------------------------
__global__ __launch_bounds__(256) void gemm3_nt(
    const ushort* __restrict__ Ahi, const ushort* __restrict__ Alo,
    const ushort* __restrict__ Bhi, const ushort* __restrict__ Blo,
    float* __restrict__ C, long long ldc) {
  __shared__ ushort smem[4 * 128 * 64];  // Ahi | Alo | Bhi | Blo (8192 each)
  const int tid = threadIdx.x;
  const int wave = tid >> 6;
  const int lane = tid & 63;
  const long long bm = (long long)blockIdx.y * 128;
  const long long bn = (long long)blockIdx.x * 128;
  const int wm = (wave & 1) * 64;
  const int wn = (wave >> 1) * 64;

  f32x4 acc[4][4];
#pragma unroll
  for (int i = 0; i < 4; ++i)
#pragma unroll
    for (int j = 0; j < 4; ++j) acc[i][j] = (f32x4){0.f, 0.f, 0.f, 0.f};

  const int r = lane >> 3;        // row within an 8-row staging issue
  const int cs = lane & 7;        // dest chunk slot (lane-contiguous LDS)
  const int csrc = cs ^ r;        // source chunk (XOR swizzle)
  const int m15 = lane & 15;
  const int kg = (lane >> 4) & 3;

  for (int kt = 0; kt < 12; ++kt) {
    const int k0 = kt * 64;
    // --- stage: each wave loads rows [wave*32, wave*32+32) of all 4 planes
#pragma unroll
    for (int s = 0; s < 4; ++s) {
      const int m0 = wave * 32 + s * 8;
      const long long arow = (bm + m0 + r) * KH + k0 + csrc * 8;
      const long long brow = (bn + m0 + r) * KH + k0 + csrc * 8;
      __builtin_amdgcn_global_load_lds(
          (const __attribute__((address_space(1))) void*)(Ahi + arow),
          (__attribute__((address_space(3))) void*)&smem[0 * 8192 + m0 * 64], 16, 0, 0);
      __builtin_amdgcn_global_load_lds(
          (const __attribute__((address_space(1))) void*)(Alo + arow),
          (__attribute__((address_space(3))) void*)&smem[1 * 8192 + m0 * 64], 16, 0, 0);
      __builtin_amdgcn_global_load_lds(
          (const __attribute__((address_space(1))) void*)(Bhi + brow),
          (__attribute__((address_space(3))) void*)&smem[2 * 8192 + m0 * 64], 16, 0, 0);
      __builtin_amdgcn_global_load_lds(
          (const __attribute__((address_space(1))) void*)(Blo + brow),
          (__attribute__((address_space(3))) void*)&smem[3 * 8192 + m0 * 64], 16, 0, 0);
    }
    __syncthreads();
    // --- compute: 2 k-steps of 32, 16 tiles, 3 mfma each
#pragma unroll
    for (int ks = 0; ks < 2; ++ks) {
      bf16x8 ah[4], al[4], bh[4], bl[4];
#pragma unroll
      for (int i = 0; i < 4; ++i) {
        const int m = wm + i * 16 + m15;
        const int slot = (ks * 4 + kg) ^ (lane & 7);  // m&7 == lane&7
        ah[i] = *(const bf16x8*)&smem[0 * 8192 + m * 64 + slot * 8];
        al[i] = *(const bf16x8*)&smem[1 * 8192 + m * 64 + slot * 8];
        const int n = wn + i * 16 + m15;
        bh[i] = *(const bf16x8*)&smem[2 * 8192 + n * 64 + slot * 8];
        bl[i] = *(const bf16x8*)&smem[3 * 8192 + n * 64 + slot * 8];
      }
#pragma unroll
      for (int i = 0; i < 4; ++i)
#pragma unroll
        for (int j = 0; j < 4; ++j) {
          acc[i][j] = __builtin_amdgcn_mfma_f32_16x16x32_bf16(ah[i], bh[j], acc[i][j], 0, 0, 0);
          acc[i][j] = __builtin_amdgcn_mfma_f32_16x16x32_bf16(ah[i], bl[j], acc[i][j], 0, 0, 0);
          acc[i][j] = __builtin_amdgcn_mfma_f32_16x16x32_bf16(al[i], bh[j], acc[i][j], 0, 0, 0);
        }
    }
    __syncthreads();
  }
  // --- epilogue: C/D layout col=lane&15 (N), row=(lane>>4)*4+reg (M)
  const int rq = (lane >> 4) * 4;
#pragma unroll
  for (int i = 0; i < 4; ++i)
#pragma unroll
    for (int j = 0; j < 4; ++j) {
      const long long n = bn + wn + j * 16 + m15;
#pragma unroll
      for (int rg = 0; rg < 4; ++rg) {
        const long long m = bm + wm + i * 16 + rq + rg;
        C[m * ldc + n] = acc[i][j][rg];
      }
    }
}

// fp32 -> bf16 hi/lo planes (float4-vectorized; n4 = elems/4)
__global__ void convertf32(const float* __restrict__ src, ushort* __restrict__ hi,
                           ushort* __restrict__ lo, int n4) {
  int i = blockIdx.x * 256 + threadIdx.x;
  if (i >= n4) return;
  float4 v = ((const float4*)src)[i];
  ushort4 h, l;
  h.x = f2bf(v.x); l.x = f2bf(v.x - bf2f(h.x));
  h.y = f2bf(v.y); l.y = f2bf(v.y - bf2f(h.y));
  h.z = f2bf(v.z); l.z = f2bf(v.z - bf2f(h.z));
  h.w = f2bf(v.w); l.w = f2bf(v.w - bf2f(h.w));
  ((ushort4*)hi)[i] = h;
  ((ushort4*)lo)[i] = l;
}

// X[b,:] = cls[b,:] + ae_weight[idx[b],:]  -> bf16 hi/lo planes
__global__ void build_x(const float* __restrict__ cls, const float* __restrict__ aew,
                        const int* __restrict__ idxbuf, ushort* __restrict__ Xhi,
                        ushort* __restrict__ Xlo) {
  int i = blockIdx.x * 256 + threadIdx.x;  // over B*H/4
  int b = i / (KH / 4);
  int c = i - b * (KH / 4);
  int idx = idxbuf[b];
  float4 cv = ((const float4*)cls)[i];
  float4 av = ((const float4*)(aew + (size_t)idx * KH))[c];
  float4 x = make_float4(cv.x + av.x, cv.y + av.y, cv.z + av.z, cv.w + av.w);
  ushort4 h, l;
  h.x = f2bf(x.x); l.x = f2bf(x.x - bf2f(h.x));
  h.y = f2bf(x.y); l.y = f2bf(x.y - bf2f(h.y));
  h.z = f2bf(x.z); l.z = f2bf(x.z - bf2f(h.z));
  h.w = f2bf(x.w); l.w = f2bf(x.w - bf2f(h.w));
  ((ushort4*)Xhi)[i] = h;
  ((ushort4*)Xlo)[i] = l;
}

// GRU gates; h (fp32) updated in place, bf16 hi/lo planes written too.
__global__ void gru_gate(const float* __restrict__ Gi, const float* __restrict__ Gh,
                         const float* __restrict__ b_ih, const float* __restrict__ b_hh,
                         float* __restrict__ h, ushort* __restrict__ hHi,
                         ushort* __restrict__ hLo, int first) {
  int i = blockIdx.x * 256 + threadIdx.x;  // over B*H
  int b = i / KH, c = i - b * KH;
  const float* gi = Gi + (size_t)b * (3 * KH);
  float ir  = gi[c]          + b_ih[c];
  float iz  = gi[c + KH]     + b_ih[c + KH];
  float in_ = gi[c + 2 * KH] + b_ih[c + 2 * KH];
  float hr = b_hh[c], hz = b_hh[c + KH], hn = b_hh[c + 2 * KH];
  float hp = 0.f;
  if (!first) {
    const float* gh = Gh + (size_t)b * (3 * KH);
    hr += gh[c]; hz += gh[c + KH]; hn += gh[c + 2 * KH];
    hp = h[i];
  }
  float rr = 1.f / (1.f + expf(-(ir + hr)));
  float z = 1.f / (1.f + expf(-(iz + hz)));
  float n = tanhf(in_ + rr * hn);
  float hv = (1.f - z) * n + z * hp;
  h[i] = hv;
  ushort hh = f2bf(hv);
  hHi[i] = hh;
  hLo[i] = f2bf(hv - bf2f(hh));
}

// One block per batch row: gumbel + mask state machine + argmax -> one-hot.
__global__ __launch_bounds__(256) void sample_step(
    float* __restrict__ out, const float* __restrict__ head_b,
    const float* __restrict__ x_, unsigned char* __restrict__ mask,
    int* __restrict__ idxbuf, int j, unsigned s0, unsigned s1) {
  const int b = blockIdx.x;
  const int tid = threadIdx.x;
  float* orow = out + ((size_t)b * KL + j) * KA;
  unsigned char* mrow = mask + (size_t)b * KA;
  const float* xrow = x_ + (size_t)b * KA;
  __shared__ float sv[256];
  __shared__ int si[256];

  int idx_prev = 0;
  if (j > 0) idx_prev = idxbuf[b];

  int empty = 0;
  if (j == 0) {
    int cnt = 0;
#pragma unroll
    for (int t = 0; t < 16; ++t) cnt += (xrow[tid + (t << 8)] != 0.f) ? 1 : 0;
    si[tid] = cnt;
    __syncthreads();
    for (int s = 128; s > 0; s >>= 1) {
      if (tid < s) si[tid] += si[tid + s];
      __syncthreads();
    }
    empty = (si[0] == 0);
    __syncthreads();
  }

  float best = -INFINITY;
  int bi = KA;
  unsigned mbits = 0;
#pragma unroll
  for (int t = 0; t < 16; ++t) {
    int a = tid + (t << 8);
    int m;
    if (j == 0) {
      m = (xrow[a] != 0.f) ? 1 : 0;
      if (empty && a == 0) m = 1;
    } else {
      m = mrow[a];
      if (idx_prev == 0) m = 0;
      if (a == 0) m = 1;
    }
    float v = -INFINITY;
    if (m) {
      unsigned o0, o1;
      tf2x32(s0, s1, 0u, (unsigned)(b * KA + a), o0, o1);
      unsigned bits = o0 ^ o1;
      float f = __uint_as_float((bits >> 9) | 0x3f800000u) - 1.0f;
      const float TINY = 1.17549435e-38f;
      float u = fmaxf(TINY, f + TINY);
      float g = -logf(-logf(u));
      v = orow[a] + head_b[a] + g;
      mbits |= (1u << t);
    }
    if (v > best || (v == best && a < bi)) { best = v; bi = a; }
  }
  sv[tid] = best; si[tid] = bi;
  __syncthreads();
  for (int s = 128; s > 0; s >>= 1) {
    if (tid < s) {
      float v2 = sv[tid + s]; int i2 = si[tid + s];
      if (v2 > sv[tid] || (v2 == sv[tid] && i2 < si[tid])) { sv[tid] = v2; si[tid] = i2; }
    }
    __syncthreads();
  }
  const int sel = si[0];
#pragma unroll
  for (int t = 0; t < 16; ++t) {
    int a = tid + (t << 8);
    int m = (mbits >> t) & 1;
    if (a == sel) m = 0;
    mrow[a] = (unsigned char)m;
    orow[a] = (a == sel) ? 1.f : 0.f;
  }
  if (tid == 0) idxbuf[b] = sel;
}

extern "C" void kernel_launch(void* const* d_in, const int* in_sizes, int n_in,
                              void* d_out, int out_size, void* d_ws, size_t ws_size,
                              hipStream_t stream) {
  const float* cls    = (const float*)d_in[0];
  const float* x_     = (const float*)d_in[1];
  const float* w_ih   = (const float*)d_in[2];
  const float* w_hh   = (const float*)d_in[3];
  const float* b_ih   = (const float*)d_in[4];
  const float* b_hh   = (const float*)d_in[5];
  const float* head_w = (const float*)d_in[6];
  const float* head_b = (const float*)d_in[7];
  const float* ae_w   = (const float*)d_in[8];
  float* out = (float*)d_out;

  char* p = (char*)d_ws;
  ushort* Xhi   = (ushort*)p; p += (size_t)KB * KH * 2;        // 6.3 MB
  ushort* Xlo   = (ushort*)p; p += (size_t)KB * KH * 2;
  ushort* hHi   = (ushort*)p; p += (size_t)KB * KH * 2;
  ushort* hLo   = (ushort*)p; p += (size_t)KB * KH * 2;
  float*  hbuf  = (float*)p;  p += (size_t)KB * KH * 4;        // 12.6 MB
  ushort* WihHi = (ushort*)p; p += (size_t)3 * KH * KH * 2;    // 3.5 MB
  ushort* WihLo = (ushort*)p; p += (size_t)3 * KH * KH * 2;
  ushort* WhhHi = (ushort*)p; p += (size_t)3 * KH * KH * 2;
  ushort* WhhLo = (ushort*)p; p += (size_t)3 * KH * KH * 2;
  ushort* HwHi  = (ushort*)p; p += (size_t)KA * KH * 2;        // 6.3 MB
  ushort* HwLo  = (ushort*)p; p += (size_t)KA * KH * 2;
  float*  Gi    = (float*)p;  p += (size_t)KB * 3 * KH * 4;    // 37.7 MB
  float*  Gh    = (float*)p;  p += (size_t)KB * 3 * KH * 4;    // 37.7 MB
  unsigned char* mask = (unsigned char*)p; p += (size_t)KB * KA;  // 16.8 MB
  int* idxbuf = (int*)p; p += (size_t)KB * 4;

  // Host-side JAX key schedule (partitionable split of key(42)).
  unsigned key0 = 0u, key1 = 42u;
  unsigned sub0[KL], sub1[KL];
  for (int j = 0; j < KL; ++j) {
    unsigned n0, n1, t0, t1;
    tf2x32(key0, key1, 0u, 0u, n0, n1);
    tf2x32(key0, key1, 0u, 1u, t0, t1);
    sub0[j] = t0; sub1[j] = t1;
    key0 = n0; key1 = n1;
  }

  // Split weights once per launch.
  convertf32<<<(3 * KH * KH / 4 + 255) / 256, 256, 0, stream>>>(w_ih, WihHi, WihLo, 3 * KH * KH / 4);
  convertf32<<<(3 * KH * KH / 4 + 255) / 256, 256, 0, stream>>>(w_hh, WhhHi, WhhLo, 3 * KH * KH / 4);
  convertf32<<<(KA * KH / 4 + 255) / 256, 256, 0, stream>>>(head_w, HwHi, HwLo, KA * KH / 4);

  for (int j = 0; j < KL; ++j) {
    if (j == 0)
      convertf32<<<(KB * KH / 4 + 255) / 256, 256, 0, stream>>>(cls, Xhi, Xlo, KB * KH / 4);
    else
      build_x<<<KB * KH / 4 / 256, 256, 0, stream>>>(cls, ae_w, idxbuf, Xhi, Xlo);
    // gi = x @ w_ih^T
    gemm3_nt<<<dim3(3 * KH / 128, KB / 128), 256, 0, stream>>>(Xhi, Xlo, WihHi, WihLo, Gi, 3 * KH);
    // gh = h @ w_hh^T (skip at j=0: h==0, gate uses b_hh only)
    if (j > 0)
      gemm3_nt<<<dim3(3 * KH / 128, KB / 128), 256, 0, stream>>>(hHi, hLo, WhhHi, WhhLo, Gh, 3 * KH);
    gru_gate<<<KB * KH / 256, 256, 0, stream>>>(Gi, Gh, b_ih, b_hh, hbuf, hHi, hLo, j == 0);
    // logits (sans bias) straight into d_out[:, j, :]
    gemm3_nt<<<dim3(KA / 128, KB / 128), 256, 0, stream>>>(hHi, hLo, HwHi, HwLo,
                                                           out + (size_t)j * KA, (long long)KL * KA);
    sample_step<<<KB, 256, 0, stream>>>(out, head_b, x_, mask, idxbuf, j, sub0[j], sub1[j]);
  }
}